// Round 3
// baseline (99.583 us; speedup 1.0000x reference)
//
#include <hip/hip_runtime.h>
#include <math.h>

#define BB 8
#define HH 384
#define WW 1280
#define LHh (HH/4)   // 96
#define LWw (WW/4)   // 320

// log-ratio helper: l = clip(log|s*m1 + a*c| - log|s*m2 + a*c|, +-10)
__device__ __forceinline__ float lr(float angv, float m1, float m2, float a) {
    float s = __sinf(angv), c = __cosf(angv);
    float q  = a * c;
    float t1 = fmaf(s, m1, q);
    float t2 = fmaf(s, m2, q);
    float l = __logf(fmaxf(fabsf(t1), 1e-6f)) - __logf(fmaxf(fabsf(t2), 1e-6f));
    return fminf(fmaxf(l, -10.0f), 10.0f);
}

// One thread per low-res cell (4x4 output tile), SCALE=2 DAG hand-unrolled.
// R3: no pointer-reinterpret of register data (SROA-safe), scalar geometry.
__global__ __launch_bounds__(256) void sno_kernel(
    const float* __restrict__ depthlow,   // B,1,LH,LW
    const float* __restrict__ ang,        // B,2,H,W
    const float* __restrict__ intr,       // B,3,3
    float* __restrict__ out)              // B,1,H,W
{
    int tid = blockIdx.x * blockDim.x + threadIdx.x;
    const int nblk = BB * LHh * LWw;
    if (tid >= nblk) return;
    int cx = tid % LWw;
    int t2 = tid / LWw;
    int cy = t2 % LHh;
    int b  = t2 / LHh;

    const float fx = intr[b*9 + 0];
    const float bx = intr[b*9 + 2];
    const float fy = intr[b*9 + 4];
    const float by = intr[b*9 + 5];
    const float rfx = 1.0f / fx;
    const float rfy = 1.0f / fy;

    const float y0f = (float)(cy * 4);
    const float x0f = (float)(cx * 4);

    // row geometry (a1 for rows 0..3; v1,v2 for rows 0..2)
    float ty0 = (y0f + 0.0f - by) * rfy;
    float ty1 = (y0f + 1.0f - by) * rfy;
    float ty2 = (y0f + 2.0f - by) * rfy;
    float ty3 = (y0f + 3.0f - by) * rfy;
    float ty4 = (y0f + 4.0f - by) * rfy;   // only for v2 row3? not needed; v2_r uses row r+1
    float a1_0 = fmaf(ty0, ty0, 1.0f);
    float a1_1 = fmaf(ty1, ty1, 1.0f);
    float a1_2 = fmaf(ty2, ty2, 1.0f);
    float a1_3 = fmaf(ty3, ty3, 1.0f);
    float v1_0 = -ty0, v1_1 = -ty1, v1_2 = -ty2;
    float v2_0 = -ty1, v2_1 = -ty2, v2_2 = -ty3;
    (void)ty4;

    // col geometry (u1 for cols 0..3; b1,b2 for cols 0..2)
    float tx0 = (x0f + 0.0f - bx) * rfx;
    float tx1 = (x0f + 1.0f - bx) * rfx;
    float tx2 = (x0f + 2.0f - bx) * rfx;
    float tx3 = (x0f + 3.0f - bx) * rfx;
    float u1_0 = fmaf(tx0, tx0, 1.0f);
    float u1_1 = fmaf(tx1, tx1, 1.0f);
    float u1_2 = fmaf(tx2, tx2, 1.0f);
    float u1_3 = fmaf(tx3, tx3, 1.0f);
    float b1_0 = -tx0, b1_1 = -tx1, b1_2 = -tx2;
    float b2_0 = -tx1, b2_1 = -tx2, b2_2 = -tx3;

    const int x0 = cx * 4;
    const size_t angbase = (size_t)b * 2 * HH * WW;
    const int y0 = cy * 4;

    // ang loads: ch0 rows 0..3, ch1 rows 0..2, each float4
    float4 ah0 = *(const float4*)(ang + angbase + (size_t)(y0 + 0) * WW + x0);
    float4 ah1 = *(const float4*)(ang + angbase + (size_t)(y0 + 1) * WW + x0);
    float4 ah2 = *(const float4*)(ang + angbase + (size_t)(y0 + 2) * WW + x0);
    float4 ah3 = *(const float4*)(ang + angbase + (size_t)(y0 + 3) * WW + x0);
    const size_t ch1 = angbase + (size_t)HH * WW;
    float4 av0 = *(const float4*)(ang + ch1 + (size_t)(y0 + 0) * WW + x0);
    float4 av1 = *(const float4*)(ang + ch1 + (size_t)(y0 + 1) * WW + x0);
    float4 av2 = *(const float4*)(ang + ch1 + (size_t)(y0 + 2) * WW + x0);

    // logh LH_rc (row r uses a1_r; col c uses b1_c,b2_c), c in 0..2
    float LH00 = lr(ah0.x, b1_0, b2_0, a1_0);
    float LH01 = lr(ah0.y, b1_1, b2_1, a1_0);
    float LH02 = lr(ah0.z, b1_2, b2_2, a1_0);
    float LH10 = lr(ah1.x, b1_0, b2_0, a1_1);
    float LH11 = lr(ah1.y, b1_1, b2_1, a1_1);
    float LH12 = lr(ah1.z, b1_2, b2_2, a1_1);
    float LH20 = lr(ah2.x, b1_0, b2_0, a1_2);
    float LH21 = lr(ah2.y, b1_1, b2_1, a1_2);
    float LH22 = lr(ah2.z, b1_2, b2_2, a1_2);
    float LH30 = lr(ah3.x, b1_0, b2_0, a1_3);
    float LH31 = lr(ah3.y, b1_1, b2_1, a1_3);
    float LH32 = lr(ah3.z, b1_2, b2_2, a1_3);

    // logv LV_rc (row r uses v1_r,v2_r; col c uses u1_c), r in 0..2
    float LV00 = lr(av0.x, v1_0, v2_0, u1_0);
    float LV01 = lr(av0.y, v1_0, v2_0, u1_1);
    float LV02 = lr(av0.z, v1_0, v2_0, u1_2);
    float LV03 = lr(av0.w, v1_0, v2_0, u1_3);
    float LV10 = lr(av1.x, v1_1, v2_1, u1_0);
    float LV11 = lr(av1.y, v1_1, v2_1, u1_1);
    float LV12 = lr(av1.z, v1_1, v2_1, u1_2);
    float LV13 = lr(av1.w, v1_1, v2_1, u1_3);
    float LV20 = lr(av2.x, v1_2, v2_2, u1_0);
    float LV21 = lr(av2.y, v1_2, v2_2, u1_1);
    float LV22 = lr(av2.z, v1_2, v2_2, u1_2);
    float LV23 = lr(av2.w, v1_2, v2_2, u1_3);

    // propagation DAG (hand-unrolled _build_paths(2), verified order)
    float D22 = __logf(depthlow[(size_t)b*LHh*LWw + (size_t)cy*LWw + cx]);
    float D21 = D22 - LH21;
    float D23 = D22 + LH22;
    float D20 = D21 - LH20;
    float D12 = D22 - LV12;
    float D11 = 0.5f*(D12 - LH11 + D21 - LV11);
    float D13 = 0.5f*(D12 + LH12 + D23 - LV13);
    float D10 = 0.5f*(D11 - LH10 + D20 - LV10);
    float D32 = D22 + LV22;
    float D31 = 0.5f*(D32 - LH31 + D21 + LV21);
    float D33 = 0.5f*(D32 + LH32 + D23 + LV23);
    float D30 = 0.5f*(D31 - LH30 + D20 + LV20);
    float D02 = D12 - LV02;
    float D01 = 0.5f*(D02 - LH01 + D11 - LV01);
    float D03 = 0.5f*(D02 + LH02 + D13 - LV03);
    float D00 = 0.5f*(D01 - LH00 + D10 - LV00);

    // write exp(D) as 4 coalesced float4 rows
    const size_t obase = (size_t)b * HH * WW + (size_t)y0 * WW + x0;
    float4 o0, o1, o2, o3;
    o0.x = __expf(D00); o0.y = __expf(D01); o0.z = __expf(D02); o0.w = __expf(D03);
    o1.x = __expf(D10); o1.y = __expf(D11); o1.z = __expf(D12); o1.w = __expf(D13);
    o2.x = __expf(D20); o2.y = __expf(D21); o2.z = __expf(D22); o2.w = __expf(D23);
    o3.x = __expf(D30); o3.y = __expf(D31); o3.z = __expf(D32); o3.w = __expf(D33);
    *(float4*)(out + obase + 0*WW) = o0;
    *(float4*)(out + obase + 1*WW) = o1;
    *(float4*)(out + obase + 2*WW) = o2;
    *(float4*)(out + obase + 3*WW) = o3;
}

extern "C" void kernel_launch(void* const* d_in, const int* in_sizes, int n_in,
                              void* d_out, int out_size, void* d_ws, size_t ws_size,
                              hipStream_t stream) {
    const float* depthlow = (const float*)d_in[0];
    const float* ang      = (const float*)d_in[1];
    const float* intr     = (const float*)d_in[2];
    float* out = (float*)d_out;

    const int nblk = BB * LHh * LWw;          // 245760
    dim3 grid((nblk + 255) / 256), block(256);
    // MEASUREMENT ROUND: launch twice (idempotent). Marginal dur vs R2
    // isolates true kernel cost from fixed harness overhead (poison fills).
    hipLaunchKernelGGL(sno_kernel, grid, block, 0, stream,
                       depthlow, ang, intr, out);
    hipLaunchKernelGGL(sno_kernel, grid, block, 0, stream,
                       depthlow, ang, intr, out);
}

// Round 4
// 88.322 us; speedup vs baseline: 1.1275x; 1.1275x over previous
//
#include <hip/hip_runtime.h>
#include <math.h>

#define BB 8
#define HH 384
#define WW 1280
#define LHh (HH/4)   // 96
#define LWw (WW/4)   // 320

// log-ratio helper: l = clip(log|s*m1 + a*c| - log|s*m2 + a*c|, +-10)
__device__ __forceinline__ float lr(float angv, float m1, float m2, float a) {
    float s = __sinf(angv), c = __cosf(angv);
    float q  = a * c;
    float t1 = fmaf(s, m1, q);
    float t2 = fmaf(s, m2, q);
    float l = __logf(fmaxf(fabsf(t1), 1e-6f)) - __logf(fmaxf(fabsf(t2), 1e-6f));
    return fminf(fmaxf(l, -10.0f), 10.0f);
}

// One thread per low-res cell (4x4 output tile), SCALE=2 DAG hand-unrolled.
// R4: single launch (R3's double launch was a measurement probe: marginal
// kernel cost ~10.1 us vs ~7.7 us memory roofline; ~80 us of dur_us is
// fixed harness poison-fill overhead we cannot touch).
__global__ __launch_bounds__(256) void sno_kernel(
    const float* __restrict__ depthlow,   // B,1,LH,LW
    const float* __restrict__ ang,        // B,2,H,W
    const float* __restrict__ intr,       // B,3,3
    float* __restrict__ out)              // B,1,H,W
{
    int tid = blockIdx.x * blockDim.x + threadIdx.x;
    const int nblk = BB * LHh * LWw;
    if (tid >= nblk) return;
    int cx = tid % LWw;
    int t2 = tid / LWw;
    int cy = t2 % LHh;
    int b  = t2 / LHh;

    const float fx = intr[b*9 + 0];
    const float bx = intr[b*9 + 2];
    const float fy = intr[b*9 + 4];
    const float by = intr[b*9 + 5];
    const float rfx = 1.0f / fx;
    const float rfy = 1.0f / fy;

    const float y0f = (float)(cy * 4);
    const float x0f = (float)(cx * 4);

    // row geometry (a1 for rows 0..3; v1,v2 for rows 0..2)
    float ty0 = (y0f + 0.0f - by) * rfy;
    float ty1 = (y0f + 1.0f - by) * rfy;
    float ty2 = (y0f + 2.0f - by) * rfy;
    float ty3 = (y0f + 3.0f - by) * rfy;
    float a1_0 = fmaf(ty0, ty0, 1.0f);
    float a1_1 = fmaf(ty1, ty1, 1.0f);
    float a1_2 = fmaf(ty2, ty2, 1.0f);
    float a1_3 = fmaf(ty3, ty3, 1.0f);
    float v1_0 = -ty0, v1_1 = -ty1, v1_2 = -ty2;
    float v2_0 = -ty1, v2_1 = -ty2, v2_2 = -ty3;

    // col geometry (u1 for cols 0..3; b1,b2 for cols 0..2)
    float tx0 = (x0f + 0.0f - bx) * rfx;
    float tx1 = (x0f + 1.0f - bx) * rfx;
    float tx2 = (x0f + 2.0f - bx) * rfx;
    float tx3 = (x0f + 3.0f - bx) * rfx;
    float u1_0 = fmaf(tx0, tx0, 1.0f);
    float u1_1 = fmaf(tx1, tx1, 1.0f);
    float u1_2 = fmaf(tx2, tx2, 1.0f);
    float u1_3 = fmaf(tx3, tx3, 1.0f);
    float b1_0 = -tx0, b1_1 = -tx1, b1_2 = -tx2;
    float b2_0 = -tx1, b2_1 = -tx2, b2_2 = -tx3;

    const int x0 = cx * 4;
    const size_t angbase = (size_t)b * 2 * HH * WW;
    const int y0 = cy * 4;

    // ang loads: ch0 rows 0..3, ch1 rows 0..2, each float4 (coalesced 16B/lane)
    float4 ah0 = *(const float4*)(ang + angbase + (size_t)(y0 + 0) * WW + x0);
    float4 ah1 = *(const float4*)(ang + angbase + (size_t)(y0 + 1) * WW + x0);
    float4 ah2 = *(const float4*)(ang + angbase + (size_t)(y0 + 2) * WW + x0);
    float4 ah3 = *(const float4*)(ang + angbase + (size_t)(y0 + 3) * WW + x0);
    const size_t ch1 = angbase + (size_t)HH * WW;
    float4 av0 = *(const float4*)(ang + ch1 + (size_t)(y0 + 0) * WW + x0);
    float4 av1 = *(const float4*)(ang + ch1 + (size_t)(y0 + 1) * WW + x0);
    float4 av2 = *(const float4*)(ang + ch1 + (size_t)(y0 + 2) * WW + x0);

    // logh LH_rc (row r uses a1_r; col c uses b1_c,b2_c), c in 0..2
    float LH00 = lr(ah0.x, b1_0, b2_0, a1_0);
    float LH01 = lr(ah0.y, b1_1, b2_1, a1_0);
    float LH02 = lr(ah0.z, b1_2, b2_2, a1_0);
    float LH10 = lr(ah1.x, b1_0, b2_0, a1_1);
    float LH11 = lr(ah1.y, b1_1, b2_1, a1_1);
    float LH12 = lr(ah1.z, b1_2, b2_2, a1_1);
    float LH20 = lr(ah2.x, b1_0, b2_0, a1_2);
    float LH21 = lr(ah2.y, b1_1, b2_1, a1_2);
    float LH22 = lr(ah2.z, b1_2, b2_2, a1_2);
    float LH30 = lr(ah3.x, b1_0, b2_0, a1_3);
    float LH31 = lr(ah3.y, b1_1, b2_1, a1_3);
    float LH32 = lr(ah3.z, b1_2, b2_2, a1_3);

    // logv LV_rc (row r uses v1_r,v2_r; col c uses u1_c), r in 0..2
    float LV00 = lr(av0.x, v1_0, v2_0, u1_0);
    float LV01 = lr(av0.y, v1_0, v2_0, u1_1);
    float LV02 = lr(av0.z, v1_0, v2_0, u1_2);
    float LV03 = lr(av0.w, v1_0, v2_0, u1_3);
    float LV10 = lr(av1.x, v1_1, v2_1, u1_0);
    float LV11 = lr(av1.y, v1_1, v2_1, u1_1);
    float LV12 = lr(av1.z, v1_1, v2_1, u1_2);
    float LV13 = lr(av1.w, v1_1, v2_1, u1_3);
    float LV20 = lr(av2.x, v1_2, v2_2, u1_0);
    float LV21 = lr(av2.y, v1_2, v2_2, u1_1);
    float LV22 = lr(av2.z, v1_2, v2_2, u1_2);
    float LV23 = lr(av2.w, v1_2, v2_2, u1_3);

    // propagation DAG (hand-unrolled _build_paths(2), verified order)
    float D22 = __logf(depthlow[(size_t)b*LHh*LWw + (size_t)cy*LWw + cx]);
    float D21 = D22 - LH21;
    float D23 = D22 + LH22;
    float D20 = D21 - LH20;
    float D12 = D22 - LV12;
    float D11 = 0.5f*(D12 - LH11 + D21 - LV11);
    float D13 = 0.5f*(D12 + LH12 + D23 - LV13);
    float D10 = 0.5f*(D11 - LH10 + D20 - LV10);
    float D32 = D22 + LV22;
    float D31 = 0.5f*(D32 - LH31 + D21 + LV21);
    float D33 = 0.5f*(D32 + LH32 + D23 + LV23);
    float D30 = 0.5f*(D31 - LH30 + D20 + LV20);
    float D02 = D12 - LV02;
    float D01 = 0.5f*(D02 - LH01 + D11 - LV01);
    float D03 = 0.5f*(D02 + LH02 + D13 - LV03);
    float D00 = 0.5f*(D01 - LH00 + D10 - LV00);

    // write exp(D) as 4 coalesced float4 rows
    const size_t obase = (size_t)b * HH * WW + (size_t)y0 * WW + x0;
    float4 o0, o1, o2, o3;
    o0.x = __expf(D00); o0.y = __expf(D01); o0.z = __expf(D02); o0.w = __expf(D03);
    o1.x = __expf(D10); o1.y = __expf(D11); o1.z = __expf(D12); o1.w = __expf(D13);
    o2.x = __expf(D20); o2.y = __expf(D21); o2.z = __expf(D22); o2.w = __expf(D23);
    o3.x = __expf(D30); o3.y = __expf(D31); o3.z = __expf(D32); o3.w = __expf(D33);
    *(float4*)(out + obase + 0*WW) = o0;
    *(float4*)(out + obase + 1*WW) = o1;
    *(float4*)(out + obase + 2*WW) = o2;
    *(float4*)(out + obase + 3*WW) = o3;
}

extern "C" void kernel_launch(void* const* d_in, const int* in_sizes, int n_in,
                              void* d_out, int out_size, void* d_ws, size_t ws_size,
                              hipStream_t stream) {
    const float* depthlow = (const float*)d_in[0];
    const float* ang      = (const float*)d_in[1];
    const float* intr     = (const float*)d_in[2];
    float* out = (float*)d_out;

    const int nblk = BB * LHh * LWw;          // 245760
    dim3 grid((nblk + 255) / 256), block(256);
    hipLaunchKernelGGL(sno_kernel, grid, block, 0, stream,
                       depthlow, ang, intr, out);
}